// Round 3
// baseline (81.064 us; speedup 1.0000x reference)
//
#include <hip/hip_runtime.h>
#include <hip/hip_bf16.h>
#include <math.h>

#define DIM 256
#define BB 1024
#define KK 128
#define PITCH 264   // bf16 elements per LDS row: 528 B, keeps 16B row alignment

typedef __attribute__((ext_vector_type(8))) short short8;
typedef __attribute__((ext_vector_type(4))) float float4v;

__device__ __forceinline__ float dot4(const float4 a, const float4 b) {
    return a.x*b.x + a.y*b.y + a.z*b.z + a.w*b.w;
}

// two f32 -> packed bf16x2 bits (RNE); lowers to v_cvt_pk_bf16_f32
__device__ __forceinline__ unsigned bf2bits(float a, float b) {
    float2 t; t.x = a; t.y = b;
    __hip_bfloat162 h = __float22bfloat162_rn(t);
    unsigned u; __builtin_memcpy(&u, &h, 4);
    return u;
}

// One block per batch element. 512 threads = 8 waves.
__global__ __launch_bounds__(512, 4) void fused_main(
    const float* __restrict__ feature,
    const float* __restrict__ text,
    const float* __restrict__ virt,
    const float* __restrict__ gumbel,
    const int*   __restrict__ ego,
    const int*   __restrict__ adj,
    float*       __restrict__ score_raw)
{
    __shared__ unsigned short tbs[KK * PITCH];   // 67584 B
    __shared__ float fpart[8][DIM];              // 8192 B
    __shared__ float spart[8];

    const int b    = blockIdx.x;
    const int tid  = threadIdx.x;
    const int wave = tid >> 6;
    const int lane = tid & 63;
    const int g    = lane >> 4;   // 16-lane group id (0..3)
    const int c    = lane & 15;   // position within group

    // lane (g,c) owns cols {64m + 4c + i} (m=0..3, i=0..3)
    float4 vm[4];
    #pragma unroll
    for (int m = 0; m < 4; ++m) vm[m] = *(const float4*)(virt + 64*m + 4*c);

    float vv2 = 0.f;
    #pragma unroll
    for (int m = 0; m < 4; ++m) vv2 += dot4(vm[m], vm[m]);
    #pragma unroll
    for (int msk = 1; msk < 16; msk <<= 1) vv2 += __shfl_xor(vv2, msk);  // ||v||^2

    const int* ego_b = ego + b * KK;
    const int  base  = wave * 16;

    // all 4 ego indices for this lane's rows, issued at once
    int eidx[4];
    #pragma unroll
    for (int it = 0; it < 4; ++it) eidx[it] = ego_b[base + it*4 + g];

    float4 fd[4];
    #pragma unroll
    for (int m = 0; m < 4; ++m) fd[m] = make_float4(0.f, 0.f, 0.f, 0.f);

    // ---- Phase A: 16 lanes per row, 4 rows per iter, prefetch 1 iter deep
    float4 nt[4], nf[4];
    {
        const float* tr = text    + (size_t)eidx[0] * DIM + 4*c;
        const float* fr = feature + (size_t)eidx[0] * DIM + 4*c;
        #pragma unroll
        for (int m = 0; m < 4; ++m) {
            nt[m] = *(const float4*)(tr + 64*m);
            nf[m] = *(const float4*)(fr + 64*m);
        }
    }

    #pragma unroll
    for (int it = 0; it < 4; ++it) {
        float4 ct[4], cf[4];
        #pragma unroll
        for (int m = 0; m < 4; ++m) { ct[m] = nt[m]; cf[m] = nf[m]; }
        if (it < 3) {
            const float* tr = text    + (size_t)eidx[it+1] * DIM + 4*c;
            const float* fr = feature + (size_t)eidx[it+1] * DIM + 4*c;
            #pragma unroll
            for (int m = 0; m < 4; ++m) {
                nt[m] = *(const float4*)(tr + 64*m);
                nf[m] = *(const float4*)(fr + 64*m);
            }
        }

        float st = 0.f, sf = 0.f, sv = 0.f;
        #pragma unroll
        for (int m = 0; m < 4; ++m) {
            st += dot4(ct[m], ct[m]);
            sf += dot4(cf[m], cf[m]);
            sv += dot4(ct[m], vm[m]);
        }
        #pragma unroll
        for (int msk = 1; msk < 16; msk <<= 1) {
            st += __shfl_xor(st, msk);
            sf += __shfl_xor(sf, msk);
            sv += __shfl_xor(sv, msk);
        }

        const float inv_ne = __builtin_amdgcn_rsqf(fmaxf(st, 1e-24f));
        const float inv_nf = __builtin_amdgcn_rsqf(fmaxf(sf, 1e-24f));
        // ||emb - v||^2 = 1 + ||v||^2 - 2 (t.v)/||t||
        const float nw2    = fmaxf(1.f + vv2 - 2.f * sv * inv_ne, 1e-24f);
        const float inv_nt = __builtin_amdgcn_rsqf(nw2);

        const int row = base + it*4 + g;
        unsigned short* dst = &tbs[row * PITCH + 4*c];
        #pragma unroll
        for (int m = 0; m < 4; ++m) {
            const float e0 = ct[m].x * inv_ne, e1 = ct[m].y * inv_ne;
            const float e2 = ct[m].z * inv_ne, e3 = ct[m].w * inv_ne;
            fd[m].x += cf[m].x * inv_nf - e0;
            fd[m].y += cf[m].y * inv_nf - e1;
            fd[m].z += cf[m].z * inv_nf - e2;
            fd[m].w += cf[m].w * inv_nf - e3;
            uint2 pk;
            pk.x = bf2bits((e0 - vm[m].x) * inv_nt, (e1 - vm[m].y) * inv_nt);
            pk.y = bf2bits((e2 - vm[m].z) * inv_nt, (e3 - vm[m].w) * inv_nt);
            *(uint2*)(dst + 64*m) = pk;
        }
    }

    // reduce f_diff partials across the 4 groups (rows of this wave)
    #pragma unroll
    for (int msk = 16; msk < 64; msk <<= 1) {
        #pragma unroll
        for (int m = 0; m < 4; ++m) {
            fd[m].x += __shfl_xor(fd[m].x, msk);
            fd[m].y += __shfl_xor(fd[m].y, msk);
            fd[m].z += __shfl_xor(fd[m].z, msk);
            fd[m].w += __shfl_xor(fd[m].w, msk);
        }
    }
    if (g == 0) {
        #pragma unroll
        for (int m = 0; m < 4; ++m)
            *(float4*)&fpart[wave][64*m + 4*c] = fd[m];
    }

    // issue gumbel loads before the barrier so they fly across it
    const float* gb = gumbel + (size_t)b * KK * KK;
    const int*   ab = adj    + (size_t)b * KK * KK;
    float gvv[32];
    #pragma unroll
    for (int r = 0; r < 4; ++r) {
        const float* gr = gb + (base + g*4 + r) * KK + c;
        #pragma unroll
        for (int t = 0; t < 8; ++t)
            gvv[r*8 + t] = __builtin_nontemporal_load(gr + t*16);
    }

    __syncthreads();

    // ---- Phase B: Gram matrix via MFMA (A-frag == B-frag loader, perm cancels)
    float4v acc[8];
    const float4v zero = {0.f, 0.f, 0.f, 0.f};
    #pragma unroll
    for (int t = 0; t < 8; ++t) acc[t] = zero;

    #pragma unroll
    for (int q = 0; q < 8; ++q) {
        const int dq = q * 32 + g * 8;
        const short8 afr = *(const short8*)&tbs[(base + c) * PITCH + dq];
        #pragma unroll
        for (int t = 0; t < 8; ++t) {
            const short8 bfr = *(const short8*)&tbs[(t*16 + c) * PITCH + dq];
            acc[t] = __builtin_amdgcn_mfma_f32_16x16x32_bf16(afr, bfr, acc[t], 0, 0, 0);
        }
    }

    int avv[32];
    #pragma unroll
    for (int r = 0; r < 4; ++r) {
        const int* ar = ab + (base + g*4 + r) * KK + c;
        #pragma unroll
        for (int t = 0; t < 8; ++t)
            avv[r*8 + t] = __builtin_nontemporal_load(ar + t*16);
    }

    // ---- softmax rows + s_diff: one 4-step tree per row (no max needed).
    // sum (adj-p)^2 = sum(adj) - invS*(2 sum(adj e) - invS sum(e^2)), p = e*invS
    float rs = 0.f;
    #pragma unroll
    for (int r = 0; r < 4; ++r) {
        float s = 0.f, a2 = 0.f, a3 = 0.f;
        int   ia = 0;
        #pragma unroll
        for (int t = 0; t < 8; ++t) {
            const float vt = acc[t][r] - 0.5f + gvv[r*8 + t];
            const float et = __expf(vt);
            const int   ad = avv[r*8 + t];
            s  += et;
            a3 += et * et;
            ia += ad;
            a2 += ad ? et : 0.f;
        }
        #pragma unroll
        for (int msk = 1; msk < 16; msk <<= 1) {
            s  += __shfl_xor(s,  msk);
            a2 += __shfl_xor(a2, msk);
            a3 += __shfl_xor(a3, msk);
            ia += __shfl_xor(ia, msk);
        }
        const float invS = __builtin_amdgcn_rcpf(s);
        const float T = (float)ia - invS * (2.f * a2 - invS * a3);
        rs += sqrtf(fmaxf(T, 0.f));
    }
    rs += __shfl_xor(rs, 16);
    rs += __shfl_xor(rs, 32);          // 16-row strip total
    if (lane == 0) spart[wave] = rs;
    __syncthreads();

    if (wave == 0) {
        float d0 = 0.f, d1 = 0.f, d2 = 0.f, d3 = 0.f;
        #pragma unroll
        for (int w = 0; w < 8; ++w) {
            d0 += fpart[w][lane];
            d1 += fpart[w][lane + 64];
            d2 += fpart[w][lane + 128];
            d3 += fpart[w][lane + 192];
        }
        const float inv = 1.f / 128.f;
        d0 *= inv; d1 *= inv; d2 *= inv; d3 *= inv;
        float q2 = d0*d0 + d1*d1 + d2*d2 + d3*d3;
        #pragma unroll
        for (int m = 1; m < 64; m <<= 1) q2 += __shfl_xor(q2, m);
        if (lane == 0) {
            float stot = 0.f;
            #pragma unroll
            for (int w = 0; w < 8; ++w) stot += spart[w];
            score_raw[b] = stot * (1.f / 128.f) + sqrtf(q2);
        }
    }
}

__global__ __launch_bounds__(1024) void finalize(
    const float* __restrict__ score_raw,
    const int*   __restrict__ label,
    float*       __restrict__ out)
{
    __shared__ float wmin[16], wmax[16], wsum[16];
    const int tid = threadIdx.x;
    const float s = score_raw[tid];
    float mn = s, mx = s;
    #pragma unroll
    for (int m = 1; m < 64; m <<= 1) {
        mn = fminf(mn, __shfl_xor(mn, m));
        mx = fmaxf(mx, __shfl_xor(mx, m));
    }
    if ((tid & 63) == 0) { wmin[tid >> 6] = mn; wmax[tid >> 6] = mx; }
    __syncthreads();
    float gmn = wmin[0], gmx = wmax[0];
    #pragma unroll
    for (int w = 1; w < 16; ++w) {
        gmn = fminf(gmn, wmin[w]);
        gmx = fmaxf(gmx, wmax[w]);
    }
    const float score = (s - gmn) / (gmx - gmn);
    out[tid] = score;

    const float y  = (float)label[tid];
    const float sc = fminf(fmaxf(score, 1e-7f), 1.f - 1e-7f);
    float term = -(y * logf(sc) + (1.f - y) * log1pf(-sc));
    #pragma unroll
    for (int m = 1; m < 64; m <<= 1) term += __shfl_xor(term, m);
    if ((tid & 63) == 0) wsum[tid >> 6] = term;
    __syncthreads();
    if (tid == 0) {
        float tot = 0.f;
        #pragma unroll
        for (int w = 0; w < 16; ++w) tot += wsum[w];
        out[BB] = tot / (1024.f * 1024.f);
    }
}

extern "C" void kernel_launch(void* const* d_in, const int* in_sizes, int n_in,
                              void* d_out, int out_size, void* d_ws, size_t ws_size,
                              hipStream_t stream) {
    const float* feature = (const float*)d_in[0];
    const float* text    = (const float*)d_in[1];
    const float* virt    = (const float*)d_in[2];
    const float* gumbel  = (const float*)d_in[3];
    const int*   ego     = (const int*)d_in[4];
    const int*   adj     = (const int*)d_in[5];
    const int*   label   = (const int*)d_in[6];
    float* out       = (float*)d_out;
    float* score_raw = (float*)d_ws;

    fused_main<<<BB, 512, 0, stream>>>(feature, text, virt, gumbel, ego, adj, score_raw);
    finalize<<<1, 1024, 0, stream>>>(score_raw, label, out);
}